// Round 12
// baseline (480.505 us; speedup 1.0000x reference)
//
#include <hip/hip_runtime.h>
#include <math.h>

// GCN: 7 graph-conv layers. N=65536 nodes, E=1048576 edges, feat 128->64(x6)->40.
// dst-CSR once per call; rank co-scheduled with gemm1; 6x fused{4-slot pull-
// aggregate + register-W GEMM, persistent waves}; final aggregate + log_softmax.

constexpr int NFEAT = 128, NHID = 64, NCLASS = 40;

typedef unsigned short ushort_t;
typedef int ivec4 __attribute__((ext_vector_type(4)));

__device__ inline ushort_t f2bf(float f) {  // round-to-nearest-even
  union { float f; unsigned int i; } v; v.f = f;
  unsigned int lsb = (v.i >> 16) & 1u;
  v.i += 0x7fffu + lsb;
  return (ushort_t)(v.i >> 16);
}

// Merged: even blocks run the L1 GEMM (S1 = x@W1, 64x64 tile); odd blocks run
// the rank histogram. gemm VALU work fills rank's atomic-latency bubbles.
__global__ __launch_bounds__(256) void rankgemm_k(
    const float* __restrict__ x, const float* __restrict__ W1,
    ushort_t* __restrict__ sout,
    const int* __restrict__ dst, int* __restrict__ cnt4,
    int* __restrict__ rank, int E, int N) {
  constexpr int HS = 68;
  __shared__ float hl[64 * HS];
  __shared__ float wl[64 * 64];
  int tid = threadIdx.x;
  int bid = blockIdx.x;

  if (bid & 1) {
    // ---- rank part: 4 edges/thread, 4 sub-histograms ----
    int i = (bid >> 1) * 256 + tid;
    int base = i * 4;
    if (base >= E) return;
    int4 d4 = *(const int4*)(dst + base);
    int r0 = atomicAdd(&cnt4[0 * N + d4.x], 1);
    int r1 = atomicAdd(&cnt4[1 * N + d4.y], 1);
    int r2 = atomicAdd(&cnt4[2 * N + d4.z], 1);
    int r3 = atomicAdd(&cnt4[3 * N + d4.w], 1);
    ivec4 rr = { (r0 << 2) | 0, (r1 << 2) | 1, (r2 << 2) | 2, (r3 << 2) | 3 };
    __builtin_nontemporal_store(rr, (ivec4*)(rank + base));
    return;
  }

  // ---- gemm part: FI=128, FO=64 ----
  int row0 = (bid >> 1) * 64;
  int tx = tid & 15, ty = tid >> 4;
  float acc[4][4] = {};
  for (int kc = 0; kc < 128; kc += 64) {
    {
      const float* hb = x + (size_t)row0 * 128 + kc;
      for (int i = tid; i < 64 * 16; i += 256) {
        int r = i >> 4, kk = (i & 15) << 2;
        float4 v = *(const float4*)(hb + (size_t)r * 128 + kk);
        *(float4*)&hl[r * HS + kk] = v;
      }
    }
    {
      const float4* Wb = (const float4*)(W1 + (size_t)kc * 64);
      for (int i = tid; i < 64 * 16; i += 256) ((float4*)wl)[i] = Wb[i];
    }
    __syncthreads();
    for (int k4 = 0; k4 < 64; k4 += 4) {
      float4 a[4];
#pragma unroll
      for (int r = 0; r < 4; ++r)
        a[r] = *(const float4*)&hl[(ty * 4 + r) * HS + k4];
#pragma unroll
      for (int j = 0; j < 4; ++j) {
        float4 bv = *(const float4*)&wl[(k4 + j) * 64 + tx * 4];
        const float* bp = (const float*)&bv;
#pragma unroll
        for (int r = 0; r < 4; ++r) {
          const float* ap = (const float*)&a[r];
#pragma unroll
          for (int c = 0; c < 4; ++c) acc[r][c] += ap[j] * bp[c];
        }
      }
    }
    __syncthreads();
  }
#pragma unroll
  for (int r = 0; r < 4; ++r) {
    ushort_t pk[4];
#pragma unroll
    for (int c = 0; c < 4; ++c) pk[c] = f2bf(acc[r][c]);
    *(ushort4*)&sout[(size_t)(row0 + ty * 4 + r) * 64 + tx * 4] =
        make_ushort4(pk[0], pk[1], pk[2], pk[3]);
  }
}

__global__ void scan1_k(const int* __restrict__ cnt4, int* __restrict__ off,
                        int* __restrict__ bsum, int4* __restrict__ sb4, int n) {
  __shared__ int tmp[256];
  int tid = threadIdx.x;
  int i = blockIdx.x * 256 + tid;
  int c0 = 0, c1 = 0, c2 = 0, c3 = 0;
  if (i < n) {
    c0 = cnt4[i]; c1 = cnt4[n + i]; c2 = cnt4[2 * n + i]; c3 = cnt4[3 * n + i];
  }
  int v = c0 + c1 + c2 + c3;
  tmp[tid] = v;
  __syncthreads();
  for (int d = 1; d < 256; d <<= 1) {
    int t = (tid >= d) ? tmp[tid - d] : 0;
    __syncthreads();
    tmp[tid] += t;
    __syncthreads();
  }
  if (i < n) {
    off[i] = tmp[tid] - v;
    sb4[i] = make_int4(0, c0, c0 + c1, c0 + c1 + c2);
  }
  if (tid == 255) bsum[blockIdx.x] = tmp[255];
}

__global__ void scan2_k(int* __restrict__ bsum, int nb) {
  __shared__ int tmp[256];
  int tid = threadIdx.x;
  int v = (tid < nb) ? bsum[tid] : 0;
  tmp[tid] = v;
  __syncthreads();
  for (int d = 1; d < 256; d <<= 1) {
    int t = (tid >= d) ? tmp[tid - d] : 0;
    __syncthreads();
    tmp[tid] += t;
    __syncthreads();
  }
  if (tid < nb) bsum[tid] = tmp[tid] - v;
}

__global__ void scan3_k(int* __restrict__ off, const int* __restrict__ bsum, int n, int E) {
  int i = blockIdx.x * blockDim.x + threadIdx.x;
  if (i < n) off[i] += bsum[i >> 8];
  if (i == 0) off[n] = E;
}

__global__ void fill_k(const int* __restrict__ src, const int* __restrict__ dst,
                       const float* __restrict__ w, const int* __restrict__ off,
                       const int* __restrict__ rank, const int* __restrict__ sb4,
                       int2* __restrict__ edata, int E) {
  int i = blockIdx.x * blockDim.x + threadIdx.x;
  int base = i * 4;
  if (base >= E) return;
  int4 s4 = *(const int4*)(src + base);
  int4 d4 = *(const int4*)(dst + base);
  float4 w4 = *(const float4*)(w + base);
  int4 r4 = *(const int4*)(rank + base);
  int dd[4] = { d4.x, d4.y, d4.z, d4.w };
  int rr[4] = { r4.x, r4.y, r4.z, r4.w };
  int ss[4] = { s4.x, s4.y, s4.z, s4.w };
  float ww[4] = { w4.x, w4.y, w4.z, w4.w };
  int ob[4], sb[4];
#pragma unroll
  for (int k = 0; k < 4; ++k) ob[k] = off[dd[k]];
#pragma unroll
  for (int k = 0; k < 4; ++k) sb[k] = sb4[dd[k] * 4 + (rr[k] & 3)];
#pragma unroll
  for (int k = 0; k < 4; ++k) {
    int pos = ob[k] + sb[k] + (rr[k] >> 2);
    int2 v = make_int2(ss[k], __float_as_int(ww[k]));
    __builtin_nontemporal_store(*(const long long*)&v, (long long*)&edata[pos]);
  }
}

// Fused 4-slot pull-aggregate + register-W GEMM, persistent waves.
// Lane = (slot = lane>>4 in 0..3: edge slot, q = lane&15: feature quad).
// Gather: dwordx2 (4 bf16) -> 4 edges per VMEM instr; meta int2 per edge.
// GEMM: lane owns column col=lane; W column held in 64 VGPRs, loaded once;
// h broadcast via 1KB LDS. Each wave processes n/nwaves nodes.
template<int FO, bool WRITE_H>
__global__ __launch_bounds__(256, 4) void aggemm_k(
    const ushort_t* __restrict__ support,   // N x 64 bf16
    const int2* __restrict__ edata,
    const int* __restrict__ off,
    const float* __restrict__ bias,         // 64
    const float* __restrict__ resid,        // N x 64 f32 or null
    const float* __restrict__ Wn,           // 64 x FO
    ushort_t* __restrict__ sout,            // N x FO bf16
    float* __restrict__ hout,               // N x 64 f32 (if WRITE_H)
    int n) {
  __shared__ float hls[4][64];
  int tid = threadIdx.x;
  int lane = tid & 63;
  int wv = tid >> 6;
  int gw = blockIdx.x * 4 + wv;
  int nwaves = gridDim.x << 2;
  int slot = lane >> 4, q = lane & 15;

  int wcol = (FO == 64) ? lane : (lane < FO ? lane : 0);
  float wreg[64];
#pragma unroll
  for (int k = 0; k < 64; ++k) wreg[k] = Wn[(size_t)k * FO + wcol];

  const ushort_t* sp = support + q * 4;

  for (int node = gw; node < n; node += nwaves) {
    int e0 = __builtin_amdgcn_readfirstlane(off[node]);
    int e1 = __builtin_amdgcn_readfirstlane(off[node + 1]);
    int deg = e1 - e0;
    const int* epi = (const int*)(edata + e0);

    float a0 = 0.f, a1 = 0.f, a2 = 0.f, a3 = 0.f;
    if (deg > 0) {
      // flat 32-edge body: 8 meta int2 loads, 8 dwordx2 gathers in flight
      int2 mt[8];
#pragma unroll
      for (int j = 0; j < 8; ++j) {
        int rel = 4 * j + slot;
        mt[j] = *(const int2*)(epi + (rel < deg ? rel : 0) * 2);
      }
      uint2 g[8];
#pragma unroll
      for (int j = 0; j < 8; ++j)
        g[j] = *(const uint2*)(sp + ((size_t)mt[j].x << 6));
#pragma unroll
      for (int j = 0; j < 8; ++j) {
        int rel = 4 * j + slot;
        float w = (rel < deg) ? __int_as_float(mt[j].y) : 0.0f;
        a0 += w * __int_as_float(g[j].x << 16);
        a1 += w * __int_as_float(g[j].x & 0xffff0000u);
        a2 += w * __int_as_float(g[j].y << 16);
        a3 += w * __int_as_float(g[j].y & 0xffff0000u);
      }
      // rare remainder (deg > 32)
      for (int it = 32; it < deg; it += 32) {
#pragma unroll
        for (int j = 0; j < 8; ++j) {
          int rel = it + 4 * j + slot;
          int2 m = *(const int2*)(epi + (rel < deg ? rel : 0) * 2);
          uint2 gg = *(const uint2*)(sp + ((size_t)m.x << 6));
          float w = (rel < deg) ? __int_as_float(m.y) : 0.0f;
          a0 += w * __int_as_float(gg.x << 16);
          a1 += w * __int_as_float(gg.x & 0xffff0000u);
          a2 += w * __int_as_float(gg.y << 16);
          a3 += w * __int_as_float(gg.y & 0xffff0000u);
        }
      }
    }
    // slot reduction (features 4q..4q+3 summed over all 32 edges)
    a0 += __shfl_xor(a0, 16, 64); a1 += __shfl_xor(a1, 16, 64);
    a2 += __shfl_xor(a2, 16, 64); a3 += __shfl_xor(a3, 16, 64);
    a0 += __shfl_xor(a0, 32, 64); a1 += __shfl_xor(a1, 32, 64);
    a2 += __shfl_xor(a2, 32, 64); a3 += __shfl_xor(a3, 32, 64);

    float4 bv = *(const float4*)&bias[q * 4];
    float v0 = fmaxf(a0 + bv.x, 0.f), v1 = fmaxf(a1 + bv.y, 0.f);
    float v2 = fmaxf(a2 + bv.z, 0.f), v3 = fmaxf(a3 + bv.w, 0.f);
    if (resid) {
      float4 r = *(const float4*)&resid[(size_t)node * 64 + q * 4];
      v0 += r.x; v1 += r.y; v2 += r.z; v3 += r.w;
    }
    if (slot == 0) {
      *(float4*)&hls[wv][q * 4] = make_float4(v0, v1, v2, v3);
      if (WRITE_H)
        *(float4*)&hout[(size_t)node * 64 + q * 4] = make_float4(v0, v1, v2, v3);
    }
    __threadfence_block();   // drain ds_write before same-wave cross-lane reads

    // GEMM: o = h . W[:,col], W in VGPRs, h broadcast from LDS
    float o = 0.f;
    const float* hb = hls[wv];
#pragma unroll
    for (int k = 0; k < 64; k += 4) {
      float4 hv = *(const float4*)&hb[k];
      o += hv.x * wreg[k] + hv.y * wreg[k + 1] + hv.z * wreg[k + 2] + hv.w * wreg[k + 3];
    }
    if (FO == 64 || lane < FO)
      sout[(size_t)node * FO + wcol] = f2bf(o);
  }
}

// Final layer: 4-slot gather over N x 40 bf16 support + bias + log_softmax.
__global__ __launch_bounds__(256, 4) void agg_final_k(
    const ushort_t* __restrict__ support,
    const int2* __restrict__ edata,
    const int* __restrict__ off,
    const float* __restrict__ bias,
    float* __restrict__ out, int n) {
  int tid = blockIdx.x * blockDim.x + threadIdx.x;
  int node = tid >> 6, lane = tid & 63;
  if (node >= n) return;
  int slot = lane >> 4, q = lane & 15;
  int qc = (q < 10) ? q : 9;        // clamp inside 40-feature row
  bool valid = (q < 10);
  int e0 = __builtin_amdgcn_readfirstlane(off[node]);
  int e1 = __builtin_amdgcn_readfirstlane(off[node + 1]);
  int deg = e1 - e0;
  const int* epi = (const int*)(edata + e0);
  const ushort_t* sp = support + qc * 4;

  float a0 = 0.f, a1 = 0.f, a2 = 0.f, a3 = 0.f;
  if (deg > 0) {
    int2 mt[8];
#pragma unroll
    for (int j = 0; j < 8; ++j) {
      int rel = 4 * j + slot;
      mt[j] = *(const int2*)(epi + (rel < deg ? rel : 0) * 2);
    }
    uint2 g[8];
#pragma unroll
    for (int j = 0; j < 8; ++j)
      g[j] = *(const uint2*)(sp + (size_t)mt[j].x * NCLASS);
#pragma unroll
    for (int j = 0; j < 8; ++j) {
      int rel = 4 * j + slot;
      float w = (rel < deg) ? __int_as_float(mt[j].y) : 0.0f;
      a0 += w * __int_as_float(g[j].x << 16);
      a1 += w * __int_as_float(g[j].x & 0xffff0000u);
      a2 += w * __int_as_float(g[j].y << 16);
      a3 += w * __int_as_float(g[j].y & 0xffff0000u);
    }
    for (int it = 32; it < deg; it += 32) {
#pragma unroll
      for (int j = 0; j < 8; ++j) {
        int rel = it + 4 * j + slot;
        int2 m = *(const int2*)(epi + (rel < deg ? rel : 0) * 2);
        uint2 gg = *(const uint2*)(sp + (size_t)m.x * NCLASS);
        float w = (rel < deg) ? __int_as_float(m.y) : 0.0f;
        a0 += w * __int_as_float(gg.x << 16);
        a1 += w * __int_as_float(gg.x & 0xffff0000u);
        a2 += w * __int_as_float(gg.y << 16);
        a3 += w * __int_as_float(gg.y & 0xffff0000u);
      }
    }
  }
  a0 += __shfl_xor(a0, 16, 64); a1 += __shfl_xor(a1, 16, 64);
  a2 += __shfl_xor(a2, 16, 64); a3 += __shfl_xor(a3, 16, 64);
  a0 += __shfl_xor(a0, 32, 64); a1 += __shfl_xor(a1, 32, 64);
  a2 += __shfl_xor(a2, 32, 64); a3 += __shfl_xor(a3, 32, 64);

  float4 bv = *(const float4*)&bias[qc * 4];
  float f0 = a0 + bv.x, f1 = a1 + bv.y, f2 = a2 + bv.z, f3 = a3 + bv.w;

  float m = valid ? fmaxf(fmaxf(f0, f1), fmaxf(f2, f3)) : -INFINITY;
#pragma unroll
  for (int d = 1; d < 16; d <<= 1) m = fmaxf(m, __shfl_xor(m, d, 64));
  float s = valid ? (expf(f0 - m) + expf(f1 - m) + expf(f2 - m) + expf(f3 - m)) : 0.0f;
#pragma unroll
  for (int d = 1; d < 16; d <<= 1) s += __shfl_xor(s, d, 64);
  float ls = logf(s);
  if (slot == 0 && valid)
    *(float4*)&out[(size_t)node * NCLASS + q * 4] =
        make_float4(f0 - m - ls, f1 - m - ls, f2 - m - ls, f3 - m - ls);
}

extern "C" void kernel_launch(void* const* d_in, const int* in_sizes, int n_in,
                              void* d_out, int out_size, void* d_ws, size_t ws_size,
                              hipStream_t stream) {
  const float* x   = (const float*)d_in[0];
  const int*   src = (const int*)d_in[1];
  const int*   dst = (const int*)d_in[2];
  const float* ew  = (const float*)d_in[3];
  const float* W[7]; const float* b[7];
  for (int i = 0; i < 7; ++i) {
    W[i] = (const float*)d_in[4 + 2 * i];
    b[i] = (const float*)d_in[5 + 2 * i];
  }
  int N = in_sizes[0] / NFEAT;   // 65536
  int E = in_sizes[1];           // 1048576

  char* ws = (char*)d_ws;
  int*      off     = (int*)(ws + 0);                 // (N+1) ints
  int*      bsum    = (int*)(ws + (1ll << 20));       // 256 ints
  int*      cnt4    = (int*)(ws + (2ll << 20));       // 4N ints = 1MB
  int4*     sb4     = (int4*)(ws + (3ll << 20));      // N int4 = 1MB
  int2*     edata   = (int2*)(ws + (4ll << 20));      // E int2 = 8MB
  int*      rank    = (int*)(ws + (12ll << 20));      // E ints = 4MB
  ushort_t* SA      = (ushort_t*)(ws + (16ll << 20)); // N*64 bf16 = 8MB
  ushort_t* SB      = (ushort_t*)(ws + (24ll << 20)); // N*64 bf16 = 8MB
  float*    hA      = (float*)(ws + (32ll << 20));    // 16MB
  float*    hB      = (float*)(ws + (48ll << 20));    // 16MB

  // ---- CSR build (rank) co-scheduled with L1 GEMM ----
  (void)hipMemsetAsync(cnt4, 0, (size_t)4 * N * sizeof(int), stream);
  rankgemm_k<<<2048, 256, 0, stream>>>(x, W[0], SA, dst, cnt4, rank, E, N);
  int nb = (N + 255) / 256;
  scan1_k<<<nb, 256, 0, stream>>>(cnt4, off, bsum, sb4, N);
  scan2_k<<<1, 256, 0, stream>>>(bsum, nb);
  scan3_k<<<nb, 256, 0, stream>>>(off, bsum, N, E);
  fill_k<<<(E / 4 + 255) / 256, 256, 0, stream>>>(src, dst, ew, off, rank,
                                                  (const int*)sb4, edata, E);

  int gb_pers = 1024;           // persistent: 4096 waves, 16 nodes/wave
  int gb_fin  = N / 4;          // 1 node/wave

  // K2: h1 = relu(agg(S1)+b1); S2 = h1@W2
  aggemm_k<64, false><<<gb_pers, 256, 0, stream>>>(SA, edata, off, b[0], nullptr,
                                                   W[1], SB, nullptr, N);
  // K3: h2 = relu(agg(S2)+b2); S3 = h2@W3; keep h2
  aggemm_k<64, true><<<gb_pers, 256, 0, stream>>>(SB, edata, off, b[1], nullptr,
                                                  W[2], SA, hA, N);
  // K4: h3 = relu(agg(S3)+b3)+h2; S4 = h3@W4; keep h3
  aggemm_k<64, true><<<gb_pers, 256, 0, stream>>>(SA, edata, off, b[2], hA,
                                                  W[3], SB, hB, N);
  // K5: h4 = relu(agg(S4)+b4)+h3; S5 = h4@W5; keep h4
  aggemm_k<64, true><<<gb_pers, 256, 0, stream>>>(SB, edata, off, b[3], hB,
                                                  W[4], SA, hA, N);
  // K6: h5 = relu(agg(S5)+b5)+h4; S6 = h5@W6
  aggemm_k<64, false><<<gb_pers, 256, 0, stream>>>(SA, edata, off, b[4], hA,
                                                   W[5], SB, nullptr, N);
  // K7: h6 = relu(agg(S6)+b6); S7 = h6@W7 (64->40)
  aggemm_k<40, false><<<gb_pers, 256, 0, stream>>>(SB, edata, off, b[5], nullptr,
                                                   W[6], SA, nullptr, N);
  // K8: out = log_softmax(agg(S7)+b7)
  agg_final_k<<<gb_fin, 256, 0, stream>>>(SA, edata, off, b[6], (float*)d_out, N);
}